// Round 14
// baseline (1461.165 us; speedup 1.0000x reference)
//
#include <hip/hip_runtime.h>
#include <stdint.h>

#define BB 8
#define CCH 64
#define NPB 4096
#define NPTS (BB*NPB)   // 32768
#define STRIP 2048

typedef float  f32x2  __attribute__((ext_vector_type(2)));
typedef float  f32x4v __attribute__((ext_vector_type(4)));
typedef short  bf16x8 __attribute__((ext_vector_type(8)));
typedef unsigned short u16x8 __attribute__((ext_vector_type(8)));
typedef unsigned long long u64;
typedef unsigned int u32;

// round-to-nearest-even f32 -> bf16 bits (monotone for nonneg inputs)
__device__ __forceinline__ unsigned short f2bf(float x) {
    u32 u = __float_as_uint(x);
    u += 0x7FFFu + ((u >> 16) & 1u);
    return (unsigned short)(u >> 16);
}

// bitonic sort16 ascending (static indices, branchless) — proven since R6
template<typename T>
__device__ __forceinline__ void sort16(T* key) {
#pragma unroll
    for (int kk = 2; kk <= 16; kk <<= 1) {
#pragma unroll
        for (int j = kk >> 1; j > 0; j >>= 1) {
#pragma unroll
            for (int i = 0; i < 16; ++i) {
                int l = i ^ j;
                if (l > i) {
                    bool up = ((i & kk) == 0);
                    T a = key[i], c = key[l];
                    bool cond = up ? (c < a) : (a < c);
                    key[i] = cond ? c : a;
                    key[l] = cond ? a : c;
                }
            }
        }
    }
}

// keep 16 smallest of (list asc, key asc) -> list asc — proven since R6
template<typename T>
__device__ __forceinline__ void merge16(T* list, const T* key) {
    T m[16];
#pragma unroll
    for (int i = 0; i < 16; ++i) {
        T a = list[i], c = key[15 - i];
        m[i] = (c < a) ? c : a;
    }
#pragma unroll
    for (int j = 8; j > 0; j >>= 1) {
#pragma unroll
        for (int i = 0; i < 16; ++i) {
            if ((i & j) == 0) {
                T a = m[i], c = m[i + j];
                bool cond = c < a;
                m[i]     = cond ? c : a;
                m[i + j] = cond ? a : c;
            }
        }
    }
#pragma unroll
    for (int i = 0; i < 16; ++i) list[i] = m[i];
}

// ---------------- K1: transpose x (B,C,N) -> xb (B,N,C) ----------------
__global__ void k_transpose(const float* __restrict__ x, float* __restrict__ xb) {
    __shared__ float tile[64][65];
    int b  = blockIdx.y;
    int n0 = blockIdx.x * 64;
    int tx = threadIdx.x, ty = threadIdx.y;   // 64 x 8
    const float* xp = x + (size_t)b * CCH * NPB;
#pragma unroll
    for (int r = 0; r < 8; ++r) {
        int c = ty + r * 8;
        tile[c][tx] = xp[(size_t)c * NPB + n0 + tx];
    }
    __syncthreads();
    float* xbp = xb + ((size_t)b * NPB + n0) * CCH;
#pragma unroll
    for (int r = 0; r < 8; ++r) {
        int nn = ty + r * 8;
        xbp[(size_t)nn * CCH + tx] = tile[tx][nn];
    }
}

// ---------------- K1b: per-point sum of squares + per-batch max ----------------
__global__ void k_sq(const float* __restrict__ xb, float* __restrict__ sq,
                     u32* __restrict__ mxbits) {
    int p = blockIdx.x * 256 + threadIdx.x;
    const float4* r = (const float4*)(xb + (size_t)p * CCH);
    float s = 0.0f;
#pragma unroll
    for (int i = 0; i < 16; ++i) {
        float4 v = r[i];
        s += v.x * v.x + v.y * v.y + v.z * v.z + v.w * v.w;
    }
    sq[p] = s;
    float m = s;
#pragma unroll
    for (int o = 32; o > 0; o >>= 1) m = fmaxf(m, __shfl_xor(m, o));
    if ((threadIdx.x & 63) == 0) atomicMax(&mxbits[p >> 12], __float_as_uint(m));
}

// ---------------- K1c: cast xb -> bf16 xh ----------------
__global__ void k_cast(const float* __restrict__ xb, unsigned short* __restrict__ xh) {
    int i = blockIdx.x * 256 + threadIdx.x;     // handles 8 elems
    const float4* s = (const float4*)(xb + (size_t)i * 8);
    float4 v0 = s[0], v1 = s[1];
    u16x8 o;
    o[0] = f2bf(v0.x); o[1] = f2bf(v0.y); o[2] = f2bf(v0.z); o[3] = f2bf(v0.w);
    o[4] = f2bf(v1.x); o[5] = f2bf(v1.y); o[6] = f2bf(v1.z); o[7] = f2bf(v1.w);
    *(u16x8*)(xh + (size_t)i * 8) = o;
}

// ---------------- K2a: bf16 MFMA distance tile (2048-row strip x 4096 cols) ----------------
// D = X * X^T via mfma_f32_16x16x32_bf16; dot is k-permutation-invariant so only
// the C/D layout matters (HW-verified: col=lane&15, row=(lane>>4)*4+reg).
// Gram symmetry absorbs any A/B role swap. Stores clamped bf16 d~2.
__global__ __launch_bounds__(256) void k_gemm(const unsigned short* __restrict__ xh,
                                              const float* __restrict__ sq,
                                              unsigned short* __restrict__ dt,
                                              int strip0) {
    int l = threadIdx.x & 63;
    int w = threadIdx.x >> 6;
    int m0 = strip0 + blockIdx.y * 64 + w * 16;
    int n0 = blockIdx.x * 64;
    const unsigned short* ap = xh + (size_t)(m0 + (l & 15)) * CCH + ((l >> 4) * 8);
    bf16x8 a0 = *(const bf16x8*)ap;
    bf16x8 a1 = *(const bf16x8*)(ap + 32);
    f32x4v z = {0.f, 0.f, 0.f, 0.f};
    f32x4v acc[4];
#pragma unroll
    for (int cg = 0; cg < 4; ++cg) {
        const unsigned short* bp = xh + (size_t)(n0 + cg * 16 + (l & 15)) * CCH + ((l >> 4) * 8);
        bf16x8 b0 = *(const bf16x8*)bp;
        bf16x8 b1 = *(const bf16x8*)(bp + 32);
        acc[cg] = __builtin_amdgcn_mfma_f32_16x16x32_bf16(a0, b0, z, 0, 0, 0);
        acc[cg] = __builtin_amdgcn_mfma_f32_16x16x32_bf16(a1, b1, acc[cg], 0, 0, 0);
    }
    int rb = m0 + (l >> 4) * 4;
    float4 sr = *(const float4*)(sq + rb);
    float sqr[4] = {sr.x, sr.y, sr.z, sr.w};
#pragma unroll
    for (int cg = 0; cg < 4; ++cg) {
        int c = n0 + cg * 16 + (l & 15);
        float sc = sq[c];
#pragma unroll
        for (int j = 0; j < 4; ++j) {
            float v = fmaxf(fmaf(-2.f, acc[cg][j], sqr[j] + sc), 0.f);
            int ris = blockIdx.y * 64 + w * 16 + (l >> 4) * 4 + j;
            dt[(size_t)ris * NPB + c] = f2bf(v);
        }
    }
}

// ---------------- K2b: per-(row, 64-col split) top-16 of stored d~ ----------------
// key32 = (bf16bits << 16) | col  (nonneg bf16 bits are order-preserving)
__global__ __launch_bounds__(256, 1) void k_top(const unsigned short* __restrict__ dt,
                                                u32* __restrict__ cand) {
    int rs = blockIdx.y * 256 + threadIdx.x;    // row in strip (per-lane)
    int split = blockIdx.x;
    int cb = split * 64;
    u32 list[16];
#pragma unroll
    for (int i = 0; i < 16; ++i) list[i] = 0xFFFFFFFFu;
    for (int t = 0; t < 4; ++t) {
        int c0 = cb + t * 16;
        const u16x8* p = (const u16x8*)(dt + (size_t)rs * NPB + c0);
        u16x8 v0 = p[0], v1 = p[1];
        u32 key[16];
#pragma unroll
        for (int i = 0; i < 8; ++i) {
            key[i]     = ((u32)v0[i] << 16) | (u32)(c0 + i);
            key[8 + i] = ((u32)v1[i] << 16) | (u32)(c0 + 8 + i);
        }
        sort16(key);
        merge16(list, key);
    }
    u32* cp = cand + ((size_t)rs * 64 + split) * 16;
#pragma unroll
    for (int i = 0; i < 16; ++i) cp[i] = list[i];
}

// ---------------- K2c: per-row threshold tau = 16th-smallest + 2*margin; zero counter ----------------
// wave per row: 64 lanes hold the 64 splits' sorted lists; 16 global pop-min rounds.
__global__ __launch_bounds__(256, 1) void k_tau(const u32* __restrict__ cand,
                                                const float* __restrict__ sqB,
                                                const u32* __restrict__ mxbits,
                                                float* __restrict__ tau,
                                                int* __restrict__ cnt,
                                                int strip0, int batch) {
    int l  = threadIdx.x & 63;
    int rl = threadIdx.x >> 6;
    int rs = blockIdx.x * 4 + rl;
    const u32* cp = cand + ((size_t)rs * 64 + l) * 16;
    u32 karr[16];
#pragma unroll
    for (int i = 0; i < 4; ++i) {
        uint4 v = *(const uint4*)(cp + i * 4);
        karr[4*i] = v.x; karr[4*i+1] = v.y; karr[4*i+2] = v.z; karr[4*i+3] = v.w;
    }
    u32 cur = karr[0];
    int idx = 0;
    u32 m = 0xFFFFFFFFu;
#pragma unroll
    for (int r = 0; r < 16; ++r) {
        u32 mv = cur;
#pragma unroll
        for (int o = 32; o > 0; o >>= 1) {
            u32 t = __shfl_xor(mv, o);
            mv = t < mv ? t : mv;
        }
        m = mv;
        if (cur == mv) {                        // unique key -> exactly one lane
            idx++;
            u32 nxt = 0xFFFFFFFFu;
#pragma unroll
            for (int q = 15; q >= 1; --q) nxt = (idx == q) ? karr[q] : nxt;
            cur = nxt;
        }
    }
    if (l == 0) {
        float f16v = __uint_as_float((m >> 16) << 16);     // strip col bits
        float sqi  = sqB[strip0 + rs];
        float M2   = __uint_as_float(mxbits[batch]);
        // |d~ - d| <= 2^-5.98*|xi||xj| (bf16 inputs) + bf16-store rounding; generous
        float margin = 0.016f * sqrtf(sqi * M2) + 0.01f * (fabsf(f16v) + 1.f) + 0.1f;
        tau[rs] = f16v + 2.f * margin;
        cnt[rs] = 0;
    }
}

// ---------------- K2d: survivor scan (stored d~ < tau) ----------------
__global__ void k_scan(const unsigned short* __restrict__ dt,
                       const float* __restrict__ tau, int* __restrict__ cnt,
                       u32* __restrict__ surv) {
    int id = blockIdx.x * 256 + threadIdx.x;    // [0, STRIP*256)
    int rs = id >> 8;
    int c0 = (id & 255) * 16;
    float t = tau[rs];
    const u16x8* p = (const u16x8*)(dt + (size_t)rs * NPB + c0);
    u16x8 v0 = p[0], v1 = p[1];
    bool hit[16]; int nh = 0;
#pragma unroll
    for (int i = 0; i < 16; ++i) {
        u32 b = (u32)(i < 8 ? v0[i] : v1[i - 8]);
        float f = __uint_as_float(b << 16);
        hit[i] = f < t;
        nh += hit[i] ? 1 : 0;
    }
    if (nh) {
        int base = atomicAdd(&cnt[rs], nh);
        int j = 0;
#pragma unroll
        for (int i = 0; i < 16; ++i) {
            if (hit[i]) {
                if (base + j < 128) surv[(size_t)rs * 128 + base + j] = (u32)(c0 + i);
                j++;
            }
        }
    }
}

// ---------------- K2e: exact fp32 d for survivors -> u64 keys ----------------
// wave per row (scalar row base -> s_load row features, R10/R11-proven pattern).
// key = (monotonic(sq[col]-2*dot) << 32) | col  (sq_row dropped: per-row constant)
__global__ __launch_bounds__(256, 1) void k_exact(const float* __restrict__ xbB,
                                                  const float* __restrict__ sqB,
                                                  const u32* __restrict__ surv,
                                                  const int* __restrict__ cnt,
                                                  u64* __restrict__ keyb,
                                                  int strip0) {
    int l  = threadIdx.x & 63;
    int rl = __builtin_amdgcn_readfirstlane(threadIdx.x >> 6);
    int rs = blockIdx.x * 4 + rl;
    const float* xr = xbB + (size_t)(strip0 + rs) * CCH;    // uniform
    float rr[64];
#pragma unroll
    for (int i = 0; i < 16; ++i) {
        float4 v = *(const float4*)(xr + i * 4);
        rr[4*i] = v.x; rr[4*i+1] = v.y; rr[4*i+2] = v.z; rr[4*i+3] = v.w;
    }
    int n = cnt[rs]; n = n < 128 ? n : 128;
#pragma unroll
    for (int pass = 0; pass < 2; ++pass) {
        int s = pass * 64 + l;
        u64 key = ~0ULL;
        if (s < n) {
            int col = (int)surv[(size_t)rs * 128 + s];
            const float* xj = xbB + (size_t)col * CCH;
            float lo = 0.f, hi = 0.f;
#pragma unroll
            for (int q = 0; q < 8; ++q) {
                float4 v  = *(const float4*)(xj + q * 4);
                float4 wv = *(const float4*)(xj + 32 + q * 4);
                lo = fmaf(v.x,  rr[4*q+0], lo);
                lo = fmaf(v.y,  rr[4*q+1], lo);
                lo = fmaf(v.z,  rr[4*q+2], lo);
                lo = fmaf(v.w,  rr[4*q+3], lo);
                hi = fmaf(wv.x, rr[32+4*q+0], hi);
                hi = fmaf(wv.y, rr[32+4*q+1], hi);
                hi = fmaf(wv.z, rr[32+4*q+2], hi);
                hi = fmaf(wv.w, rr[32+4*q+3], hi);
            }
            float d = fmaf(-2.f, lo + hi, sqB[col]);
            u32 fb = __float_as_uint(d);
            fb ^= (fb >> 31) ? 0xFFFFFFFFu : 0x80000000u;
            key = ((u64)fb << 32) | (u32)col;
        }
        keyb[(size_t)rs * 128 + s] = key;
    }
}

// ---------------- K2f: per-row top-16 of survivor keys -> idx ----------------
// 8 rows/wave: lane = (row-in-wave, chunk); chunk sort16 + 3-stage shfl merge tree.
__global__ __launch_bounds__(256, 1) void k_sel(const u64* __restrict__ keyb,
                                                int* __restrict__ idxo) {
    int l  = threadIdx.x & 63;
    int wv = threadIdx.x >> 6;
    int rl = l >> 3, g = l & 7;
    int rs = blockIdx.x * 32 + wv * 8 + rl;
    u64 k[16];
    const u64* kp = keyb + (size_t)rs * 128 + g * 16;
#pragma unroll
    for (int i = 0; i < 16; ++i) k[i] = kp[i];
    sort16(k);
#pragma unroll
    for (int st = 1; st <= 4; st <<= 1) {
        u64 pk[16];
#pragma unroll
        for (int i = 0; i < 16; ++i)
            pk[i] = (u64)__shfl_xor((long long)k[i], st);
        merge16(k, pk);
    }
    if (g == 0) {
#pragma unroll
        for (int i = 0; i < 16; ++i)
            idxo[(size_t)rs * 16 + i] = (int)(k[i] & 0xFFFFFFFFu);
    }
}

// ---------------- K4: fused edge-MLP + max over K (R12/R13 body, proven) ----------------
__global__ __launch_bounds__(256, 1) void k_mlp(const float* __restrict__ xb,
                                                const int* __restrict__ idx,
                                                const float* __restrict__ W1,
                                                const float* __restrict__ b1,
                                                const float* __restrict__ W2,
                                                const float* __restrict__ b2,
                                                float* __restrict__ out) {
    int lane = threadIdx.x & 63;
    int wib  = __builtin_amdgcn_readfirstlane(threadIdx.x >> 6);
    int wave = blockIdx.x * 4 + wib;
    int o = lane;
    f32x2 wa2[32], wb2[32];
    float w2r[64];
#pragma unroll
    for (int c = 0; c < 32; ++c) {
        float w1a0 = W1[(2*c) * 64 + o];
        float w1b0 = W1[(64 + 2*c) * 64 + o];
        float w1a1 = W1[(2*c + 1) * 64 + o];
        float w1b1 = W1[(64 + 2*c + 1) * 64 + o];
        wa2[c] = (f32x2){w1a0 - w1b0, w1a1 - w1b1};
        wb2[c] = (f32x2){w1b0, w1b1};
    }
#pragma unroll
    for (int c = 0; c < 64; ++c) w2r[c] = W2[c * 64 + o];
    float bb1 = b1[o], bb2 = b2[o];
    int p0 = wave * 16;
    for (int pi = 0; pi < 16; ++pi) {
        int p = p0 + pi;
        int b = p >> 12;
        int n = p & 4095;
        const float* xbB = xb + ((size_t)b << 12) * CCH;
        const float* xi = xbB + (size_t)n * CCH;
        f32x2 acc1 = {bb1, 0.f};
        const f32x2* xi2 = (const f32x2*)xi;
#pragma unroll
        for (int e = 0; e < 32; ++e) acc1 += xi2[e] * wa2[e];
        float pre = acc1.x + acc1.y;
        const int* ip = idx + (size_t)p * 16;
        float mx = 0.f;
        for (int k = 0; k < 16; ++k) {
            int j = ip[k];
            const float* xj = xbB + (size_t)j * CCH;
            const f32x2* xj2 = (const f32x2*)xj;
            f32x2 acch = {0.f, 0.f};
#pragma unroll
            for (int e = 0; e < 32; ++e) acch += xj2[e] * wb2[e];
            float h1 = fmaxf(pre + acch.x + acch.y, 0.f);
            float a0 = bb2, a1 = 0.f, a2 = 0.f, a3 = 0.f;
#pragma unroll
            for (int j4 = 0; j4 < 16; ++j4) {
                float h0  = __int_as_float(__builtin_amdgcn_readlane(__float_as_int(h1), 4*j4+0));
                float hh1 = __int_as_float(__builtin_amdgcn_readlane(__float_as_int(h1), 4*j4+1));
                float h2  = __int_as_float(__builtin_amdgcn_readlane(__float_as_int(h1), 4*j4+2));
                float h3  = __int_as_float(__builtin_amdgcn_readlane(__float_as_int(h1), 4*j4+3));
                a0 = fmaf(h0,  w2r[4*j4+0], a0);
                a1 = fmaf(hh1, w2r[4*j4+1], a1);
                a2 = fmaf(h2,  w2r[4*j4+2], a2);
                a3 = fmaf(h3,  w2r[4*j4+3], a3);
            }
            float acc = (a0 + a1) + (a2 + a3);
            float h2o = fmaxf(acc, 0.f);
            mx = fmaxf(mx, h2o);
        }
        out[((size_t)b * 64 + o) * NPB + n] = mx;
    }
}

extern "C" void kernel_launch(void* const* d_in, const int* in_sizes, int n_in,
                              void* d_out, int out_size, void* d_ws, size_t ws_size,
                              hipStream_t stream) {
    const float* x  = (const float*)d_in[0];
    const float* W1 = (const float*)d_in[1];
    const float* b1 = (const float*)d_in[2];
    const float* W2 = (const float*)d_in[3];
    const float* b2 = (const float*)d_in[4];
    float* out = (float*)d_out;

    const size_t MB = 1024 * 1024;
    char* ws = (char*)d_ws;
    float*          xb   = (float*)(ws);                        // 8 MB
    unsigned short* xh   = (unsigned short*)(ws + 8 * MB);      // 4 MB
    float*          sq   = (float*)(ws + 12 * MB);              // 128 KB
    u32*            mx   = (u32*)(ws + 12 * MB + 131072);       // 32 B
    unsigned short* dt   = (unsigned short*)(ws + 13 * MB);     // 16 MB (strip)
    u32*            cand = (u32*)(ws + 29 * MB);                // 8 MB
    float*          tau  = (float*)(ws + 37 * MB);              // 8 KB
    int*            cnt  = (int*)(ws + 37 * MB + 8192);         // 8 KB
    u32*            surv = (u32*)(ws + 38 * MB);                // 1 MB
    u64*            keyb = (u64*)(ws + 39 * MB);                // 2 MB
    int*            idxb = (int*)(ws + 41 * MB);                // 2 MB

    hipMemsetAsync(mx, 0, BB * sizeof(u32), stream);
    hipLaunchKernelGGL(k_transpose, dim3(NPB / 64, BB), dim3(64, 8), 0, stream, x, xb);
    hipLaunchKernelGGL(k_sq, dim3(NPTS / 256), dim3(256), 0, stream, xb, sq, mx);
    hipLaunchKernelGGL(k_cast, dim3(NPTS * CCH / 8 / 256), dim3(256), 0, stream, xb, xh);

    for (int b = 0; b < BB; ++b) {
        const unsigned short* xhB = xh + (size_t)b * NPB * CCH;
        const float* xbB = xb + (size_t)b * NPB * CCH;
        const float* sqB = sq + (size_t)b * NPB;
        for (int h = 0; h < 2; ++h) {
            int strip0 = h * STRIP;
            hipLaunchKernelGGL(k_gemm, dim3(NPB / 64, STRIP / 64), dim3(256), 0, stream,
                               xhB, sqB, dt, strip0);
            hipLaunchKernelGGL(k_top, dim3(64, STRIP / 256), dim3(256), 0, stream, dt, cand);
            hipLaunchKernelGGL(k_tau, dim3(STRIP / 4), dim3(256), 0, stream,
                               cand, sqB, mx, tau, cnt, strip0, b);
            hipLaunchKernelGGL(k_scan, dim3(STRIP * (NPB / 16) / 256), dim3(256), 0, stream,
                               dt, tau, cnt, surv);
            hipLaunchKernelGGL(k_exact, dim3(STRIP / 4), dim3(256), 0, stream,
                               xbB, sqB, surv, cnt, keyb, strip0);
            hipLaunchKernelGGL(k_sel, dim3(STRIP / 32), dim3(256), 0, stream,
                               keyb, idxb + ((size_t)b * NPB + strip0) * 16);
        }
    }
    hipLaunchKernelGGL(k_mlp, dim3(512), dim3(256), 0, stream, xb, idxb, W1, b1, W2, b2, out);
}

// Round 15
// 677.574 us; speedup vs baseline: 2.1565x; 2.1565x over previous
//
#include <hip/hip_runtime.h>
#include <stdint.h>

#define BB 8
#define CCH 64
#define NPB 4096
#define NPTS (BB*NPB)   // 32768

typedef float  f32x2  __attribute__((ext_vector_type(2)));
typedef float  f32x4v __attribute__((ext_vector_type(4)));
typedef short  bf16x8 __attribute__((ext_vector_type(8)));
typedef unsigned short u16x8 __attribute__((ext_vector_type(8)));
typedef unsigned long long u64;
typedef unsigned int u32;

// round-to-nearest-even f32 -> bf16 bits (monotone for nonneg inputs)
__device__ __forceinline__ unsigned short f2bf(float x) {
    u32 u = __float_as_uint(x);
    u += 0x7FFFu + ((u >> 16) & 1u);
    return (unsigned short)(u >> 16);
}

// bitonic sort16 ascending (static indices, branchless) — proven since R6
template<typename T>
__device__ __forceinline__ void sort16(T* key) {
#pragma unroll
    for (int kk = 2; kk <= 16; kk <<= 1) {
#pragma unroll
        for (int j = kk >> 1; j > 0; j >>= 1) {
#pragma unroll
            for (int i = 0; i < 16; ++i) {
                int l = i ^ j;
                if (l > i) {
                    bool up = ((i & kk) == 0);
                    T a = key[i], c = key[l];
                    bool cond = up ? (c < a) : (a < c);
                    key[i] = cond ? c : a;
                    key[l] = cond ? a : c;
                }
            }
        }
    }
}

// keep 16 smallest of (list asc, key asc) -> list asc — proven since R6
template<typename T>
__device__ __forceinline__ void merge16(T* list, const T* key) {
    T m[16];
#pragma unroll
    for (int i = 0; i < 16; ++i) {
        T a = list[i], c = key[15 - i];
        m[i] = (c < a) ? c : a;
    }
#pragma unroll
    for (int j = 8; j > 0; j >>= 1) {
#pragma unroll
        for (int i = 0; i < 16; ++i) {
            if ((i & j) == 0) {
                T a = m[i], c = m[i + j];
                bool cond = c < a;
                m[i]     = cond ? c : a;
                m[i + j] = cond ? a : c;
            }
        }
    }
#pragma unroll
    for (int i = 0; i < 16; ++i) list[i] = m[i];
}

// ---------------- K1: transpose x (B,C,N) -> xb (B,N,C) ----------------
__global__ void k_transpose(const float* __restrict__ x, float* __restrict__ xb) {
    __shared__ float tile[64][65];
    int b  = blockIdx.y;
    int n0 = blockIdx.x * 64;
    int tx = threadIdx.x, ty = threadIdx.y;   // 64 x 8
    const float* xp = x + (size_t)b * CCH * NPB;
#pragma unroll
    for (int r = 0; r < 8; ++r) {
        int c = ty + r * 8;
        tile[c][tx] = xp[(size_t)c * NPB + n0 + tx];
    }
    __syncthreads();
    float* xbp = xb + ((size_t)b * NPB + n0) * CCH;
#pragma unroll
    for (int r = 0; r < 8; ++r) {
        int nn = ty + r * 8;
        xbp[(size_t)nn * CCH + tx] = tile[tx][nn];
    }
}

// ---------------- K1b: per-point sum of squares ----------------
__global__ void k_sq(const float* __restrict__ xb, float* __restrict__ sq) {
    int p = blockIdx.x * 256 + threadIdx.x;
    const float4* r = (const float4*)(xb + (size_t)p * CCH);
    float s = 0.0f;
#pragma unroll
    for (int i = 0; i < 16; ++i) {
        float4 v = r[i];
        s += v.x * v.x + v.y * v.y + v.z * v.z + v.w * v.w;
    }
    sq[p] = s;
}

// ---------------- K1c: cast xb -> bf16 xh ----------------
__global__ void k_cast(const float* __restrict__ xb, unsigned short* __restrict__ xh) {
    int i = blockIdx.x * 256 + threadIdx.x;     // handles 8 elems
    const float4* s = (const float4*)(xb + (size_t)i * 8);
    float4 v0 = s[0], v1 = s[1];
    u16x8 o;
    o[0] = f2bf(v0.x); o[1] = f2bf(v0.y); o[2] = f2bf(v0.z); o[3] = f2bf(v0.w);
    o[4] = f2bf(v1.x); o[5] = f2bf(v1.y); o[6] = f2bf(v1.z); o[7] = f2bf(v1.w);
    *(u16x8*)(xh + (size_t)i * 8) = o;
}

// ---------------- K2: MFMA 64x64 distance tile + fused per-row block top-16 ----------------
// MFMA loads + d~ epilogue math byte-identical to R14's PASSING k_gemm
// (C/D layout: col=lane&15, row=(lane>>4)*4+reg). LDS transpose (dtile) then
// per-lane sort16 per 16-col chunk + cross-chunk merge -> cand[bx][row][16]
// sorted u32 keys ((bf16bits<<16)|col, unique -> (d~ asc, col asc)).
__global__ __launch_bounds__(256) void k_gemm(const unsigned short* __restrict__ xh,
                                              const float* __restrict__ sq,
                                              u32* __restrict__ cand) {
    __shared__ float dtile[64][65];
    __shared__ u32 llist[64][65];
    int l = threadIdx.x & 63;
    int w = threadIdx.x >> 6;
    int m0 = blockIdx.y * 64;
    int n0 = blockIdx.x * 64;
    const unsigned short* ap = xh + (size_t)(m0 + w * 16 + (l & 15)) * CCH + ((l >> 4) * 8);
    bf16x8 a0 = *(const bf16x8*)ap;
    bf16x8 a1 = *(const bf16x8*)(ap + 32);
    f32x4v z = {0.f, 0.f, 0.f, 0.f};
    f32x4v acc[4];
#pragma unroll
    for (int cg = 0; cg < 4; ++cg) {
        const unsigned short* bp = xh + (size_t)(n0 + cg * 16 + (l & 15)) * CCH + ((l >> 4) * 8);
        bf16x8 b0 = *(const bf16x8*)bp;
        bf16x8 b1 = *(const bf16x8*)(bp + 32);
        acc[cg] = __builtin_amdgcn_mfma_f32_16x16x32_bf16(a0, b0, z, 0, 0, 0);
        acc[cg] = __builtin_amdgcn_mfma_f32_16x16x32_bf16(a1, b1, acc[cg], 0, 0, 0);
    }
    int rb = m0 + w * 16 + (l >> 4) * 4;
    float4 sr = *(const float4*)(sq + rb);
    float sqr[4] = {sr.x, sr.y, sr.z, sr.w};
#pragma unroll
    for (int cg = 0; cg < 4; ++cg) {
        int cit = cg * 16 + (l & 15);
        float sc = sq[n0 + cit];
#pragma unroll
        for (int j = 0; j < 4; ++j) {
            float v = fmaxf(fmaf(-2.f, acc[cg][j], sqr[j] + sc), 0.f);
            dtile[w * 16 + (l >> 4) * 4 + j][cit] = v;
        }
    }
    __syncthreads();
    // phase 2: wave w sorts chunk w for all 64 rows (lane = row)
    {
        int row = l, ch = w;
        u32 key[16];
#pragma unroll
        for (int e = 0; e < 16; ++e) {
            float v = dtile[row][ch * 16 + e];
            key[e] = ((u32)f2bf(v) << 16) | (u32)(n0 + ch * 16 + e);
        }
        sort16(key);
#pragma unroll
        for (int i = 0; i < 16; ++i) llist[row][ch * 16 + i] = key[i];
    }
    __syncthreads();
    // phase 3: threads 0..63 merge the 4 chunk lists of their row
    if (threadIdx.x < 64) {
        int r2 = threadIdx.x;
        u32 list[16], tmp[16];
#pragma unroll
        for (int i = 0; i < 16; ++i) list[i] = llist[r2][i];
#pragma unroll
        for (int ch2 = 1; ch2 < 4; ++ch2) {
#pragma unroll
            for (int i = 0; i < 16; ++i) tmp[i] = llist[r2][ch2 * 16 + i];
            merge16(list, tmp);
        }
        u32* cp = cand + ((size_t)blockIdx.x * NPB + (m0 + r2)) * 16;
#pragma unroll
        for (int i = 0; i < 16; ++i) cp[i] = list[i];
    }
}

// ---------------- K3: per-row pop-48 + exact fp32 refine -> idx ----------------
// wave per row. lane l holds block-l's sorted 16. 48 wave-min pop rounds
// gather the 48 smallest d~ candidates (round r -> lane r); those lanes
// compute exact fp32 d (R14 k_exact's byte-identical order; rr wave-uniform
// -> s_load); final 16 wave-min rounds by exact u64 (d,col) key.
__global__ __launch_bounds__(256, 1) void k_post(const u32* __restrict__ cand,
                                                 const float* __restrict__ xbB,
                                                 const float* __restrict__ sqB,
                                                 int* __restrict__ idxo) {
    int l  = threadIdx.x & 63;
    int rl = __builtin_amdgcn_readfirstlane(threadIdx.x >> 6);
    int row = blockIdx.x * 4 + rl;              // scalar
    const float* xr = xbB + (size_t)row * CCH;  // uniform
    float rr[64];
#pragma unroll
    for (int i = 0; i < 16; ++i) {
        float4 v = *(const float4*)(xr + i * 4);
        rr[4*i] = v.x; rr[4*i+1] = v.y; rr[4*i+2] = v.z; rr[4*i+3] = v.w;
    }
    u32 karr[16];
    {
        const uint4* cp = (const uint4*)(cand + ((size_t)l * NPB + row) * 16);
#pragma unroll
        for (int i = 0; i < 4; ++i) {
            uint4 v = cp[i];
            karr[4*i] = v.x; karr[4*i+1] = v.y; karr[4*i+2] = v.z; karr[4*i+3] = v.w;
        }
    }
    u32 cur = karr[0];
    int ci = 0;
    u32 mycol = 0xFFFFFFFFu;
#pragma unroll
    for (int r = 0; r < 48; ++r) {
        u32 mv = cur;
#pragma unroll
        for (int o = 32; o > 0; o >>= 1) {
            u32 t = __shfl_xor(mv, o);
            mv = t < mv ? t : mv;
        }
        if (l == r) mycol = mv;                 // unique key -> one winner
        if (cur == mv) {
            ci++;
            u32 nxt = 0xFFFFFFFFu;
#pragma unroll
            for (int q = 15; q >= 1; --q) nxt = (ci == q) ? karr[q] : nxt;
            cur = nxt;
        }
    }
    u64 mykey = ~0ULL;
    if (mycol != 0xFFFFFFFFu) {
        int col = (int)(mycol & 0xFFFFu);
        const float* xj = xbB + (size_t)col * CCH;
        float lo = 0.f, hi = 0.f;
#pragma unroll
        for (int q = 0; q < 8; ++q) {
            float4 v  = *(const float4*)(xj + q * 4);
            float4 wv = *(const float4*)(xj + 32 + q * 4);
            lo = fmaf(v.x,  rr[4*q+0], lo);
            lo = fmaf(v.y,  rr[4*q+1], lo);
            lo = fmaf(v.z,  rr[4*q+2], lo);
            lo = fmaf(v.w,  rr[4*q+3], lo);
            hi = fmaf(wv.x, rr[32+4*q+0], hi);
            hi = fmaf(wv.y, rr[32+4*q+1], hi);
            hi = fmaf(wv.z, rr[32+4*q+2], hi);
            hi = fmaf(wv.w, rr[32+4*q+3], hi);
        }
        float d = fmaf(-2.f, lo + hi, sqB[col]);
        u32 fb = __float_as_uint(d);
        fb ^= (fb >> 31) ? 0xFFFFFFFFu : 0x80000000u;   // monotonic
        mykey = ((u64)fb << 32) | (u32)col;
    }
    u64 curk = mykey;
#pragma unroll
    for (int r = 0; r < 16; ++r) {
        u64 mv = curk;
#pragma unroll
        for (int o = 32; o > 0; o >>= 1) {
            u64 t = (u64)__shfl_xor((long long)mv, o);
            mv = t < mv ? t : mv;
        }
        if (curk == mv) curk = ~0ULL;           // pop (keys unique)
        if (l == 0) idxo[(size_t)row * 16 + r] = (int)(mv & 0xFFFFFFFFu);
    }
}

// ---------------- K4: fused edge-MLP + max over K ----------------
// R12/R13 proven body; 8 points/wave (4096 waves = 2x occupancy vs R14's
// 2048: hides the s_load row-gather latency seen at VALUBusy 57%).
__global__ __launch_bounds__(256, 1) void k_mlp(const float* __restrict__ xb,
                                                const int* __restrict__ idx,
                                                const float* __restrict__ W1,
                                                const float* __restrict__ b1,
                                                const float* __restrict__ W2,
                                                const float* __restrict__ b2,
                                                float* __restrict__ out) {
    int lane = threadIdx.x & 63;
    int wib  = __builtin_amdgcn_readfirstlane(threadIdx.x >> 6);
    int wave = blockIdx.x * 4 + wib;            // scalar 0..4095
    int o = lane;
    f32x2 wa2[32], wb2[32];
    float w2r[64];
#pragma unroll
    for (int c = 0; c < 32; ++c) {
        float w1a0 = W1[(2*c) * 64 + o];
        float w1b0 = W1[(64 + 2*c) * 64 + o];
        float w1a1 = W1[(2*c + 1) * 64 + o];
        float w1b1 = W1[(64 + 2*c + 1) * 64 + o];
        wa2[c] = (f32x2){w1a0 - w1b0, w1a1 - w1b1};
        wb2[c] = (f32x2){w1b0, w1b1};
    }
#pragma unroll
    for (int c = 0; c < 64; ++c) w2r[c] = W2[c * 64 + o];
    float bb1 = b1[o], bb2 = b2[o];
    int p0 = wave * 8;
    for (int pi = 0; pi < 8; ++pi) {
        int p = p0 + pi;                        // scalar
        int b = p >> 12;
        int n = p & 4095;
        const float* xbB = xb + ((size_t)b << 12) * CCH;    // scalar base
        const float* xi = xbB + (size_t)n * CCH;            // scalar
        f32x2 acc1 = {bb1, 0.f};
        const f32x2* xi2 = (const f32x2*)xi;
#pragma unroll
        for (int e = 0; e < 32; ++e) acc1 += xi2[e] * wa2[e];   // v_pk_fma
        float pre = acc1.x + acc1.y;
        const int* ip = idx + (size_t)p * 16;   // scalar
        float mx = 0.f;
        for (int k = 0; k < 16; ++k) {
            int j = ip[k];                      // scalar (uniform load)
            const float* xj = xbB + (size_t)j * CCH;        // scalar
            const f32x2* xj2 = (const f32x2*)xj;
            f32x2 acch = {0.f, 0.f};
#pragma unroll
            for (int e = 0; e < 32; ++e) acch += xj2[e] * wb2[e];   // v_pk_fma
            float h1 = fmaxf(pre + acch.x + acch.y, 0.f);
            float a0 = bb2, a1 = 0.f, a2 = 0.f, a3 = 0.f;
#pragma unroll
            for (int j4 = 0; j4 < 16; ++j4) {
                float h0  = __int_as_float(__builtin_amdgcn_readlane(__float_as_int(h1), 4*j4+0));
                float hh1 = __int_as_float(__builtin_amdgcn_readlane(__float_as_int(h1), 4*j4+1));
                float h2  = __int_as_float(__builtin_amdgcn_readlane(__float_as_int(h1), 4*j4+2));
                float h3  = __int_as_float(__builtin_amdgcn_readlane(__float_as_int(h1), 4*j4+3));
                a0 = fmaf(h0,  w2r[4*j4+0], a0);
                a1 = fmaf(hh1, w2r[4*j4+1], a1);
                a2 = fmaf(h2,  w2r[4*j4+2], a2);
                a3 = fmaf(h3,  w2r[4*j4+3], a3);
            }
            float acc = (a0 + a1) + (a2 + a3);
            float h2o = fmaxf(acc, 0.f);
            mx = fmaxf(mx, h2o);
        }
        out[((size_t)b * 64 + o) * NPB + n] = mx;
    }
}

extern "C" void kernel_launch(void* const* d_in, const int* in_sizes, int n_in,
                              void* d_out, int out_size, void* d_ws, size_t ws_size,
                              hipStream_t stream) {
    const float* x  = (const float*)d_in[0];
    const float* W1 = (const float*)d_in[1];
    const float* b1 = (const float*)d_in[2];
    const float* W2 = (const float*)d_in[3];
    const float* b2 = (const float*)d_in[4];
    float* out = (float*)d_out;

    const size_t MB = 1024 * 1024;
    char* ws = (char*)d_ws;
    float*          xb   = (float*)(ws);                        // 8 MB
    unsigned short* xh   = (unsigned short*)(ws + 8 * MB);      // 4 MB
    float*          sq   = (float*)(ws + 12 * MB);              // 128 KB
    u32*            cand = (u32*)(ws + 13 * MB);                // 16.78 MB
    int*            idxb = (int*)(ws + 30 * MB);                // 2 MB

    hipLaunchKernelGGL(k_transpose, dim3(NPB / 64, BB), dim3(64, 8), 0, stream, x, xb);
    hipLaunchKernelGGL(k_sq, dim3(NPTS / 256), dim3(256), 0, stream, xb, sq);
    hipLaunchKernelGGL(k_cast, dim3(NPTS * CCH / 8 / 256), dim3(256), 0, stream, xb, xh);

    for (int b = 0; b < BB; ++b) {
        const unsigned short* xhB = xh + (size_t)b * NPB * CCH;
        const float* xbB = xb + (size_t)b * NPB * CCH;
        const float* sqB = sq + (size_t)b * NPB;
        hipLaunchKernelGGL(k_gemm, dim3(NPB / 64, NPB / 64), dim3(256), 0, stream,
                           xhB, sqB, cand);
        hipLaunchKernelGGL(k_post, dim3(NPB / 4), dim3(256), 0, stream,
                           cand, xbB, sqB, idxb + (size_t)b * NPB * 16);
    }
    hipLaunchKernelGGL(k_mlp, dim3(1024), dim3(256), 0, stream, xb, idxb, W1, b1, W2, b2, out);
}